// Round 6
// baseline (3246.279 us; speedup 1.0000x reference)
//
#include <hip/hip_runtime.h>
#include <cstddef>

#define B_ 8
#define L_ 2048
#define D_ 1024
#define NL_ 16
#define H_ 64
#define E_ 16
#define S_ 256
#define CAT_ 5120

using u16 = unsigned short;

// bf16 <-> f32 for the temb workspace only (outputs are all fp32!)
__device__ __forceinline__ float b2f(u16 u){ return __uint_as_float(((unsigned)u)<<16); }
__device__ __forceinline__ u16 f2b(float f){
  const unsigned u = __float_as_uint(f);
  return (u16)((u + 0x7FFFu + ((u>>16)&1u)) >> 16);
}

// ---------------- reduction helpers (wave = 64) ----------------
__device__ __forceinline__ float wave_sum(float v){
#pragma unroll
  for(int o=32;o;o>>=1) v += __shfl_down(v,o);
  return v;
}
__device__ __forceinline__ float wave_max(float v){
#pragma unroll
  for(int o=32;o;o>>=1) v = fmaxf(v, __shfl_down(v,o));
  return v;
}
__device__ __forceinline__ float block_sum256(float v, float* sm){
  v = wave_sum(v);
  const int lane = threadIdx.x & 63, w = threadIdx.x >> 6;
  if(lane==0) sm[w] = v;
  __syncthreads();
  const float r = (sm[0]+sm[1])+(sm[2]+sm[3]);
  __syncthreads();
  return r;
}
__device__ __forceinline__ float block_max256(float v, float* sm){
  v = wave_max(v);
  const int lane = threadIdx.x & 63, w = threadIdx.x >> 6;
  if(lane==0) sm[w] = v;
  __syncthreads();
  const float r = fmaxf(fmaxf(sm[0],sm[1]), fmaxf(sm[2],sm[3]));
  __syncthreads();
  return r;
}

#define FMA4(m, hval) { acc[m][0]+=(hval)*av.x; acc[m][1]+=(hval)*av.y; acc[m][2]+=(hval)*av.z; acc[m][3]+=(hval)*av.w; }

// ---------------- cast embedding fp32 -> bf16 workspace ----------------
__global__ __launch_bounds__(256) void k_cast(
    const float* __restrict__ in, u16* __restrict__ out){
  const size_t i = ((size_t)blockIdx.x*256 + threadIdx.x)*4;
  const float4 v = *(const float4*)(in + i);
  ushort4 o; o.x=f2b(v.x); o.y=f2b(v.y); o.z=f2b(v.z); o.w=f2b(v.w);
  *(ushort4*)(out + i) = o;
}

// ---------------- score[b,h,l] = emb_row . att_w[h]  (full K=1024) ----------
__global__ __launch_bounds__(256) void k_score(
    const u16* __restrict__ embB, const float* __restrict__ wq,
    float* __restrict__ score, int layer){
  __shared__ float As[16][68];
  __shared__ float Ws[16][68];
  const int tid = threadIdx.x;
  const int m0 = blockIdx.x * 64;            // row tile in [0, B*L)
  const int b  = m0 >> 11;
  const int l0 = m0 & (L_-1);
  const float* W = wq + (size_t)layer*(H_*D_);
  const int row = tid >> 2;
  const int kq  = (tid & 3) * 4;
  const int tx = tid & 15, ty = tid >> 4;
  float acc[4][4] = {};
  for(int k0=0;k0<D_;k0+=16){
    const ushort4 a = *(const ushort4*)(embB + (size_t)(m0+row)*D_ + k0 + kq);
    const float4 w4 = *(const float4*)(W + (size_t)row*D_ + k0 + kq);
    As[kq+0][row]=b2f(a.x); As[kq+1][row]=b2f(a.y); As[kq+2][row]=b2f(a.z); As[kq+3][row]=b2f(a.w);
    Ws[kq+0][row]=w4.x;     Ws[kq+1][row]=w4.y;     Ws[kq+2][row]=w4.z;     Ws[kq+3][row]=w4.w;
    __syncthreads();
#pragma unroll
    for(int kk=0;kk<16;kk++){
      const float4 av = *(const float4*)&As[kk][tx*4];
      const float4 hv = *(const float4*)&Ws[kk][ty*4];
      FMA4(0, hv.x) FMA4(1, hv.y) FMA4(2, hv.z) FMA4(3, hv.w)
    }
    __syncthreads();
  }
#pragma unroll
  for(int mm=0;mm<4;mm++){
    const int h = ty*4+mm;
    float4 v; v.x=acc[mm][0]; v.y=acc[mm][1]; v.z=acc[mm][2]; v.w=acc[mm][3];
    *(float4*)(score + (size_t)(b*H_ + h)*L_ + l0 + tx*4) = v;
  }
}

// ------------- softmax over L per (b,h): att -> out_ta (fp32 output) --------
__global__ __launch_bounds__(256) void k_softmax(
    const float* __restrict__ score, const float* __restrict__ att_b,
    float* __restrict__ out_ta, int layer){
  __shared__ float sm[4];
  const int bh = blockIdx.x;                 // b*H + h
  const int h = bh & (H_-1);
  const int t = threadIdx.x;
  const float bias = att_b[layer*H_ + h];
  const float* p0 = score + (size_t)bh*L_;
  float v[8]; float mx = 0.f;
#pragma unroll
  for(int j=0;j<8;j++){
    v[j] = fmaxf(p0[t + j*256] + bias, 0.f);   // relu(score + b)
    mx = fmaxf(mx, v[j]);
  }
  mx = block_max256(mx, sm);
  float sum = 0.f;
#pragma unroll
  for(int j=0;j<8;j++){ v[j] = __expf(v[j]-mx); sum += v[j]; }
  sum = block_sum256(sum, sm);
  const float inv = 1.f/sum;
  float* orow = out_ta + ((size_t)layer*(B_*H_) + bh)*L_;
#pragma unroll
  for(int j=0;j<8;j++) orow[t + j*256] = v[j]*inv;
}

// ------------- s-partials = att(f32) @ emb(bf16), k-split x2, no atomics ----
__global__ __launch_bounds__(256) void k_sgemm(
    const u16* __restrict__ embB, const float* __restrict__ ta,
    float* __restrict__ part){
  __shared__ float As[16][68];
  __shared__ float Bs[16][68];
  const int tid = threadIdx.x;
  const int n0 = blockIdx.x * 64;            // d-tile
  const int kbase = blockIdx.y * 1024;       // k-split over L
  const int b = blockIdx.z;
  const int rowA = tid >> 2, kqA = (tid & 3)*4;
  const int rowB = tid >> 4, nqB = (tid & 15)*4;
  const int tx = tid & 15, ty = tid >> 4;
  float acc[4][4] = {};
  for(int k0=kbase;k0<kbase+1024;k0+=16){
    const float4 a = *(const float4*)(ta + (size_t)(b*H_ + rowA)*L_ + k0 + kqA);
    As[kqA+0][rowA]=a.x; As[kqA+1][rowA]=a.y; As[kqA+2][rowA]=a.z; As[kqA+3][rowA]=a.w;
    const ushort4 e4 = *(const ushort4*)(embB + (size_t)(b*L_ + k0 + rowB)*D_ + n0 + nqB);
    Bs[rowB][nqB+0]=b2f(e4.x); Bs[rowB][nqB+1]=b2f(e4.y); Bs[rowB][nqB+2]=b2f(e4.z); Bs[rowB][nqB+3]=b2f(e4.w);
    __syncthreads();
#pragma unroll
    for(int kk=0;kk<16;kk++){
      const float4 av = *(const float4*)&Bs[kk][tx*4];   // 4 d-values
      const float4 hv = *(const float4*)&As[kk][ty*4];   // 4 h-values
      FMA4(0, hv.x) FMA4(1, hv.y) FMA4(2, hv.z) FMA4(3, hv.w)
    }
    __syncthreads();
  }
  float* o = part + (size_t)blockIdx.y*((size_t)B_*H_*D_);
#pragma unroll
  for(int mm=0;mm<4;mm++){
    const int h = ty*4+mm;
    float4 v; v.x=acc[mm][0]; v.y=acc[mm][1]; v.z=acc[mm][2]; v.w=acc[mm][3];
    *(float4*)(o + (size_t)(b*H_ + h)*D_ + n0 + tx*4) = v;
  }
}

// ------------- LN((p0+p1)/sqrt(L))*g+b then vec=relu(. @ pro_w^T + pro_b) ---
__global__ __launch_bounds__(256) void k_vec(
    const float* __restrict__ part, const float* __restrict__ g,
    const float* __restrict__ bb, const float* __restrict__ pw,
    const float* __restrict__ pb, float* __restrict__ outvec, int layer){
  __shared__ float sm[4];
  __shared__ float lnS[D_];
  const int bh = blockIdx.x;
  const int b = bh >> 6, h = bh & 63;
  const int t = threadIdx.x;
  const float scale = 0.02209708691207961f;   // 1/sqrt(2048)
  const float4 xa = *(const float4*)(part + (size_t)bh*D_ + t*4);
  const float4 xb = *(const float4*)(part + (size_t)B_*H_*D_ + (size_t)bh*D_ + t*4);
  float x0=(xa.x+xb.x)*scale, x1=(xa.y+xb.y)*scale, x2=(xa.z+xb.z)*scale, x3=(xa.w+xb.w)*scale;
  const float mean = block_sum256(x0+x1+x2+x3, sm) * (1.f/D_);
  const float d0=x0-mean, d1=x1-mean, d2=x2-mean, d3=x3-mean;
  const float var = block_sum256(d0*d0+d1*d1+d2*d2+d3*d3, sm) * (1.f/D_);
  const float inv = rsqrtf(var + 1e-5f);
  const float4 g4 = *(const float4*)(g + ((size_t)layer*H_ + h)*D_ + t*4);
  const float4 b4 = *(const float4*)(bb + ((size_t)layer*H_ + h)*D_ + t*4);
  lnS[t*4+0] = d0*inv*g4.x + b4.x;
  lnS[t*4+1] = d1*inv*g4.y + b4.y;
  lnS[t*4+2] = d2*inv*g4.z + b4.z;
  lnS[t*4+3] = d3*inv*g4.w + b4.w;
  __syncthreads();
  const int e = t >> 4, sub = t & 15;
  const float* W = pw + (((size_t)layer*H_ + h)*E_ + e)*D_;
  float p = 0.f;
#pragma unroll 4
  for(int j=0;j<64;j++){ const int d = sub + j*16; p += lnS[d]*W[d]; }
#pragma unroll
  for(int o=8;o;o>>=1) p += __shfl_down(p,o,16);
  if(sub==0){
    const float vv = fmaxf(p + pb[((size_t)layer*H_ + h)*E_ + e], 0.f);
    outvec[b*D_ + e*H_ + h] = vv;   // out[b, e*H+h] = vec[b,h,e]
  }
}

// ------------- out2 = relu(out @ fi_w^T + fi_b) + out -----------------------
__global__ __launch_bounds__(256) void k_fi(
    const float* __restrict__ outvec, const float* __restrict__ fw,
    const float* __restrict__ fb, float* __restrict__ out2, int layer){
  __shared__ float xs[D_];
  __shared__ float ps[256];
  const int b = blockIdx.y;
  const int j0 = blockIdx.x * 64;
  const int t = threadIdx.x;
  *(float4*)&xs[t*4] = *(const float4*)(outvec + b*D_ + t*4);
  __syncthreads();
  const int j = t & 63, q = t >> 6;
  const float* W = fw + ((size_t)layer*D_ + j0 + j)*D_ + q*256;
  const float* xq = xs + q*256;
  float p = 0.f;
#pragma unroll 4
  for(int d=0;d<256;d+=4){
    const float4 w4 = *(const float4*)&W[d];
    p += w4.x*xq[d+0] + w4.y*xq[d+1] + w4.z*xq[d+2] + w4.w*xq[d+3];
  }
  ps[t] = p;
  __syncthreads();
  if(t < 64){
    const float sum = ps[t] + ps[t+64] + ps[t+128] + ps[t+192];
    out2[b*D_ + j0 + t] = fmaxf(sum + fb[layer*D_ + j0 + t], 0.f) + xs[j0 + t];
  }
}

// ------------- ott[:, i*S:(i+1)*S] = relu(out2 @ set_w^T + set_b) -----------
__global__ __launch_bounds__(256) void k_set(
    const float* __restrict__ out2, const float* __restrict__ sw,
    const float* __restrict__ sb, float* __restrict__ ott, int layer){
  __shared__ float xs[D_];
  __shared__ float ps[256];
  const int b = blockIdx.y;
  const int s0 = blockIdx.x * 64;
  const int t = threadIdx.x;
  *(float4*)&xs[t*4] = *(const float4*)(out2 + b*D_ + t*4);
  __syncthreads();
  const int j = t & 63, q = t >> 6;
  const float* W = sw + ((size_t)layer*S_ + s0 + j)*D_ + q*256;
  const float* xq = xs + q*256;
  float p = 0.f;
#pragma unroll 4
  for(int d=0;d<256;d+=4){
    const float4 w4 = *(const float4*)&W[d];
    p += w4.x*xq[d+0] + w4.y*xq[d+1] + w4.z*xq[d+2] + w4.w*xq[d+3];
  }
  ps[t] = p;
  __syncthreads();
  if(t < 64){
    const float sum = ps[t] + ps[t+64] + ps[t+128] + ps[t+192];
    ott[b*(NL_*S_) + layer*S_ + s0 + t] = fmaxf(sum + sb[layer*S_ + s0 + t], 0.f);
  }
}

// --- att_sum (over h) + dis out(fp32) + t_emb = LN(t_emb*(asum*pw+pb)+t_emb)
__global__ __launch_bounds__(256) void k_update(
    u16* __restrict__ tembB, const float* __restrict__ ta,
    const float* __restrict__ pw, const float* __restrict__ pb,
    const float* __restrict__ ng, const float* __restrict__ nb,
    float* __restrict__ out_dis, int layer){
  __shared__ float sm[4];
  __shared__ float ash;
  const int rowid = blockIdx.x;              // b*L + l
  const int b = rowid >> 11, l = rowid & (L_-1);
  const int t = threadIdx.x;
  float av = 0.f;
  if(t < H_) av = ta[(size_t)(b*H_ + t)*L_ + l];
  av = wave_sum(av);
  if(t == 0){
    ash = av;
    out_dis[((size_t)layer*B_ + b)*L_ + l] = av;
  }
  __syncthreads();
  const float asum = ash;
  const ushort4 xu = *(const ushort4*)(tembB + (size_t)rowid*D_ + t*4);
  const float x0=b2f(xu.x), x1=b2f(xu.y), x2=b2f(xu.z), x3=b2f(xu.w);
  const float4 w4 = *(const float4*)(pw + layer*D_ + t*4);
  const float4 b4 = *(const float4*)(pb + layer*D_ + t*4);
  float y0 = x0*(asum*w4.x + b4.x) + x0;
  float y1 = x1*(asum*w4.y + b4.y) + x1;
  float y2 = x2*(asum*w4.z + b4.z) + x2;
  float y3 = x3*(asum*w4.w + b4.w) + x3;
  const float mean = block_sum256(y0+y1+y2+y3, sm)*(1.f/D_);
  y0-=mean; y1-=mean; y2-=mean; y3-=mean;
  const float var = block_sum256(y0*y0+y1*y1+y2*y2+y3*y3, sm)*(1.f/D_);
  const float inv = rsqrtf(var + 1e-5f);
  const float4 g4 = *(const float4*)(ng + layer*D_ + t*4);
  const float4 n4 = *(const float4*)(nb + layer*D_ + t*4);
  ushort4 o;
  o.x = f2b(y0*inv*g4.x + n4.x);
  o.y = f2b(y1*inv*g4.y + n4.y);
  o.z = f2b(y2*inv*g4.z + n4.z);
  o.w = f2b(y3*inv*g4.w + n4.w);
  *(ushort4*)(tembB + (size_t)rowid*D_ + t*4) = o;
}

// ------------- final: fscore = relu(t_emb @ aat_w + aat_b) ------------------
__global__ __launch_bounds__(256) void k_fscore(
    const u16* __restrict__ embB, const float* __restrict__ aw,
    const float* __restrict__ ab, float* __restrict__ out){
  __shared__ float sm[4];
  const int row = blockIdx.x, t = threadIdx.x;
  const ushort4 xu = *(const ushort4*)(embB + (size_t)row*D_ + t*4);
  const float4 w = *(const float4*)(aw + t*4);
  float p = b2f(xu.x)*w.x + b2f(xu.y)*w.y + b2f(xu.z)*w.z + b2f(xu.w)*w.w;
  p = block_sum256(p, sm);
  if(t==0) out[row] = fmaxf(p + ab[0], 0.f);
}

__global__ __launch_bounds__(256) void k_fsoftmax(
    float* __restrict__ fsc, float* __restrict__ out_fa){
  __shared__ float sm[4];
  const int b = blockIdx.x, t = threadIdx.x;
  float* row = fsc + (size_t)b*L_;
  float v[8]; float mx = 0.f;
#pragma unroll
  for(int j=0;j<8;j++){ v[j]=row[t+j*256]; mx=fmaxf(mx,v[j]); }
  mx = block_max256(mx, sm);
  float sum=0.f;
#pragma unroll
  for(int j=0;j<8;j++){ v[j]=__expf(v[j]-mx); sum+=v[j]; }
  sum = block_sum256(sum, sm);
  const float inv = 1.f/sum;
#pragma unroll
  for(int j=0;j<8;j++){
    const float a = v[j]*inv;
    row[t+j*256] = a;
    out_fa[(size_t)b*L_ + t+j*256] = a;
  }
}

// ------------- fpart[c][b][d] = sum over 256 l of att*emb (no atomics) ------
__global__ __launch_bounds__(256) void k_fsum(
    const u16* __restrict__ embB, const float* __restrict__ fsc,
    float* __restrict__ fpart){
  const int b = blockIdx.y, c = blockIdx.x;
  const int l0 = c*256;
  const int t = threadIdx.x;
  float a0=0,a1=0,a2=0,a3=0;
  for(int r=0;r<256;r++){
    const float a = fsc[(size_t)b*L_ + l0 + r];
    const ushort4 xu = *(const ushort4*)(embB + (size_t)(b*L_ + l0 + r)*D_ + t*4);
    a0 += a*b2f(xu.x); a1 += a*b2f(xu.y); a2 += a*b2f(xu.z); a3 += a*b2f(xu.w);
  }
  const float sc = 0.02209708691207961f;  // 1/sqrt(2048)
  float4 v; v.x=a0*sc; v.y=a1*sc; v.z=a2*sc; v.w=a3*sc;
  *(float4*)(fpart + (size_t)c*(B_*D_) + b*D_ + t*4) = v;
}

__global__ __launch_bounds__(256) void k_final(
    const float* __restrict__ fpart, const float* __restrict__ g,
    const float* __restrict__ bb, const float* __restrict__ ott,
    const float* __restrict__ h2w, const float* __restrict__ h2b,
    float* __restrict__ outP){
  __shared__ float sm[4];
  __shared__ float lnS[D_];
  const int b = blockIdx.x, t = threadIdx.x;
  float x0=0,x1=0,x2=0,x3=0;
#pragma unroll
  for(int c=0;c<8;c++){
    const float4 v = *(const float4*)(fpart + (size_t)c*(B_*D_) + b*D_ + t*4);
    x0+=v.x; x1+=v.y; x2+=v.z; x3+=v.w;
  }
  const float mean = block_sum256(x0+x1+x2+x3, sm)*(1.f/D_);
  const float d0=x0-mean, d1=x1-mean, d2=x2-mean, d3=x3-mean;
  const float var = block_sum256(d0*d0+d1*d1+d2*d2+d3*d3, sm)*(1.f/D_);
  const float inv = rsqrtf(var+1e-5f);
  const float4 g4 = *(const float4*)(g + t*4);
  const float4 b4 = *(const float4*)(bb + t*4);
  lnS[t*4+0]=d0*inv*g4.x+b4.x;
  lnS[t*4+1]=d1*inv*g4.y+b4.y;
  lnS[t*4+2]=d2*inv*g4.z+b4.z;
  lnS[t*4+3]=d3*inv*g4.w+b4.w;
  __syncthreads();
  float p=0.f;
  for(int idx=t; idx<CAT_; idx+=256){
    const float v = (idx < D_) ? lnS[idx] : ott[b*(NL_*S_) + idx - D_];
    p += v*h2w[idx];
  }
  p = block_sum256(p, sm);
  if(t==0){
    const float z = p + h2b[0];
    outP[b] = 1.f/(1.f+__expf(-z));
  }
}

extern "C" void kernel_launch(void* const* d_in, const int* in_sizes, int n_in,
                              void* d_out, int out_size, void* d_ws, size_t ws_size,
                              hipStream_t stream){
  (void)in_sizes; (void)n_in; (void)out_size; (void)ws_size;
  const float* embding  = (const float*)d_in[0];
  const float* att_w    = (const float*)d_in[1];
  const float* att_b    = (const float*)d_in[2];
  const float* att_ln_g = (const float*)d_in[3];
  const float* att_ln_b = (const float*)d_in[4];
  const float* pro_w    = (const float*)d_in[5];
  const float* pro_b    = (const float*)d_in[6];
  const float* proj_w   = (const float*)d_in[7];
  const float* proj_b   = (const float*)d_in[8];
  const float* fi_w     = (const float*)d_in[9];
  const float* fi_b     = (const float*)d_in[10];
  const float* set_w    = (const float*)d_in[11];
  const float* set_b    = (const float*)d_in[12];
  const float* norm_g   = (const float*)d_in[13];
  const float* norm_b   = (const float*)d_in[14];
  const float* aat_w    = (const float*)d_in[15];
  const float* aat_b    = (const float*)d_in[16];
  const float* aat_ln_g = (const float*)d_in[17];
  const float* aat_ln_b = (const float*)d_in[18];
  const float* h2p_w    = (const float*)d_in[19];
  const float* h2p_b    = (const float*)d_in[20];

  // Outputs are FLOAT32 (reference returns fp32; round-4 evidence bit-exact).
  float* out     = (float*)d_out;
  float* outP    = out;                          // [B,1]          @ 0
  float* out_dis = out + 8;                      // [NL,B,L,1]     @ 8
  float* out_ta  = out + 262152;                 // [NL,B,H,L,1]   @ 262152
  float* out_fa  = out + 17039368;               // [B,L,1]        @ 17039368

  // Workspace (~36.8 MB):
  float* ws = (float*)d_ws;
  float* R      = ws;                  // 1,048,576 f: score [B,H,L] OR s-partials [2][B,H,D]
  float* outvec = R + 1048576;         // 8192 f
  float* out2   = outvec + 8192;       // 8192 f
  float* ott    = out2 + 8192;         // 32768 f
  float* fpart  = ott + 32768;         // 65536 f : [8][B,D]
  float* fscore = fpart + 65536;       // 16384 f
  u16*   tembB  = (u16*)(fscore + 16384);  // 16,777,216 bf16 (32 MB)

  k_cast<<<16384, 256, 0, stream>>>(embding, tembB);

  for(int i=0;i<NL_;i++){
    const float* ta_l = out_ta + (size_t)i*((size_t)B_*H_*L_);
    k_score  <<<256,          256, 0, stream>>>(tembB, att_w, R, i);
    k_softmax<<<512,          256, 0, stream>>>(R, att_b, out_ta, i);
    k_sgemm  <<<dim3(16,2,8), 256, 0, stream>>>(tembB, ta_l, R);
    k_vec    <<<512,          256, 0, stream>>>(R, att_ln_g, att_ln_b, pro_w, pro_b, outvec, i);
    k_fi     <<<dim3(16,8),   256, 0, stream>>>(outvec, fi_w, fi_b, out2, i);
    k_set    <<<dim3(4,8),    256, 0, stream>>>(out2, set_w, set_b, ott, i);
    k_update <<<16384,        256, 0, stream>>>(tembB, ta_l, proj_w, proj_b, norm_g, norm_b,
                                                out_dis, i);
  }
  k_fscore  <<<16384,     256, 0, stream>>>(tembB, aat_w, aat_b, fscore);
  k_fsoftmax<<<8,         256, 0, stream>>>(fscore, out_fa);
  k_fsum    <<<dim3(8,8), 256, 0, stream>>>(tembB, fscore, fpart);
  k_final   <<<8,         256, 0, stream>>>(fpart, aat_ln_g, aat_ln_b, ott, h2p_w, h2p_b, outP);
}